// Round 2
// baseline (2211.656 us; speedup 1.0000x reference)
//
#include <hip/hip_runtime.h>
#include <hip/hip_bf16.h>

#define N_NODES 50000
#define N_EDGES 800000
// dims: NDIM_IN = EDIM = NDIM_OUT = 64

// ---------------------------------------------------------------------------
// Kernel 1: scatter-add edge features by dst + count edges per dst.
// sums = d_out h-region (zeroed by memset), cnt = first 50000 floats of eh region.
// ---------------------------------------------------------------------------
__global__ void scatter_kernel(const float* __restrict__ efeats,
                               const int* __restrict__ dst,
                               float* __restrict__ sums,
                               float* __restrict__ cnt) {
    int idx = blockIdx.x * 256 + threadIdx.x;   // E*64 = 51.2M threads, exact grid
    int e = idx >> 6;
    int d = idx & 63;
    int dn = dst[e];
    atomicAdd(&sums[dn * 64 + d], efeats[idx]);
    if (d == 0) atomicAdd(&cnt[dn], 1.0f);
}

// ---------------------------------------------------------------------------
// Kernel 2: h = relu(W_a [nfeat || sum/max(cnt,1)] + b).  Thread per row.
// In-place: reads sums from h[], writes h[] (each thread owns its row).
// W loads are wave-uniform -> s_load + v_fmac(sgpr,vgpr).
// ---------------------------------------------------------------------------
__global__ void __launch_bounds__(64) node_kernel(const float* __restrict__ nfeats,
                                                  const float* __restrict__ W,   // [64][128]
                                                  const float* __restrict__ bias,
                                                  const float* __restrict__ cnt,
                                                  float* __restrict__ h) {
    int n = blockIdx.x * 64 + threadIdx.x;
    if (n >= N_NODES) return;
    float inv = 1.0f / fmaxf(cnt[n], 1.0f);

    float acc[64];
#pragma unroll
    for (int j = 0; j < 64; ++j) acc[j] = bias[j];

    const float* __restrict__ xn = nfeats + (size_t)n * 64;
    const float* __restrict__ xs = h + (size_t)n * 64;

#pragma unroll 1
    for (int kc = 0; kc < 8; ++kc) {
        float xv[8];
#pragma unroll
        for (int i = 0; i < 8; ++i) xv[i] = xn[kc * 8 + i];
#pragma unroll
        for (int j = 0; j < 64; ++j)
#pragma unroll
            for (int i = 0; i < 8; ++i)
                acc[j] = fmaf(W[j * 128 + kc * 8 + i], xv[i], acc[j]);
    }
#pragma unroll 1
    for (int kc = 0; kc < 8; ++kc) {
        float xv[8];
#pragma unroll
        for (int i = 0; i < 8; ++i) xv[i] = xs[kc * 8 + i] * inv;
#pragma unroll
        for (int j = 0; j < 64; ++j)
#pragma unroll
            for (int i = 0; i < 8; ++i)
                acc[j] = fmaf(W[j * 128 + 64 + kc * 8 + i], xv[i], acc[j]);
    }

    float* out = h + (size_t)n * 64;
#pragma unroll
    for (int j = 0; j < 64; j += 4) {
        float4 v = make_float4(fmaxf(acc[j + 0], 0.0f), fmaxf(acc[j + 1], 0.0f),
                               fmaxf(acc[j + 2], 0.0f), fmaxf(acc[j + 3], 0.0f));
        *(float4*)(out + j) = v;
    }
}

// ---------------------------------------------------------------------------
// Kernel 3: eh = relu(W_e [h[src] || h[dst] || ef] + b).  Thread per edge.
// 12288 FMA/thread at 1 instr/MAC (scalar W operand). Coalesced stores via
// padded-LDS transpose ([128][65]: writes (t+j)%32 banks, reads 2/bank).
// ---------------------------------------------------------------------------
__global__ void __launch_bounds__(128) edge_kernel(const float* __restrict__ efeats,
                                                   const int* __restrict__ src,
                                                   const int* __restrict__ dst,
                                                   const float* __restrict__ h,
                                                   const float* __restrict__ W,   // [64][192]
                                                   const float* __restrict__ bias,
                                                   float* __restrict__ eh) {
    __shared__ float tile[128][65];
    const int t = threadIdx.x;
    const int e = blockIdx.x * 128 + t;          // E = 6250*128, exact

    const int s = src[e];
    const int d = dst[e];

    float acc[64];
#pragma unroll
    for (int j = 0; j < 64; ++j) acc[j] = bias[j];

    const float* __restrict__ x0 = h + (size_t)s * 64;
    const float* __restrict__ x1 = h + (size_t)d * 64;
    const float* __restrict__ x2 = efeats + (size_t)e * 64;

#pragma unroll 1
    for (int kc = 0; kc < 8; ++kc) {
        float xv[8];
#pragma unroll
        for (int i = 0; i < 8; ++i) xv[i] = x0[kc * 8 + i];
#pragma unroll
        for (int j = 0; j < 64; ++j)
#pragma unroll
            for (int i = 0; i < 8; ++i)
                acc[j] = fmaf(W[j * 192 + kc * 8 + i], xv[i], acc[j]);
    }
#pragma unroll 1
    for (int kc = 0; kc < 8; ++kc) {
        float xv[8];
#pragma unroll
        for (int i = 0; i < 8; ++i) xv[i] = x1[kc * 8 + i];
#pragma unroll
        for (int j = 0; j < 64; ++j)
#pragma unroll
            for (int i = 0; i < 8; ++i)
                acc[j] = fmaf(W[j * 192 + 64 + kc * 8 + i], xv[i], acc[j]);
    }
#pragma unroll 1
    for (int kc = 0; kc < 8; ++kc) {
        float xv[8];
#pragma unroll
        for (int i = 0; i < 8; ++i) xv[i] = x2[kc * 8 + i];
#pragma unroll
        for (int j = 0; j < 64; ++j)
#pragma unroll
            for (int i = 0; i < 8; ++i)
                acc[j] = fmaf(W[j * 192 + 128 + kc * 8 + i], xv[i], acc[j]);
    }

    // transpose through LDS -> fully coalesced dwordx4 global stores
#pragma unroll
    for (int j = 0; j < 64; ++j) tile[t][j] = fmaxf(acc[j], 0.0f);
    __syncthreads();

    float4* outp = (float4*)(eh + (size_t)blockIdx.x * (128 * 64));
#pragma unroll
    for (int it = 0; it < 16; ++it) {
        int f = it * 128 + t;                 // float4 index in block tile (2048 total)
        int row = f >> 4;
        int c0 = (f & 15) << 2;
        outp[f] = make_float4(tile[row][c0], tile[row][c0 + 1],
                              tile[row][c0 + 2], tile[row][c0 + 3]);
    }
}

// ---------------------------------------------------------------------------
extern "C" void kernel_launch(void* const* d_in, const int* in_sizes, int n_in,
                              void* d_out, int out_size, void* d_ws, size_t ws_size,
                              hipStream_t stream) {
    const float* nfeats = (const float*)d_in[0];
    const float* efeats = (const float*)d_in[1];
    const int*   src    = (const int*)d_in[2];
    const int*   dst    = (const int*)d_in[3];
    const float* Wa     = (const float*)d_in[4];
    const float* ba     = (const float*)d_in[5];
    const float* We     = (const float*)d_in[6];
    const float* be     = (const float*)d_in[7];

    float* out = (float*)d_out;
    float* h   = out;                               // [50000*64], first seg-sums, then h
    float* eh  = out + (size_t)N_NODES * 64;        // [800000*64]
    float* cnt = eh;                                // 50000 floats, overwritten later by eh

    // zero seg-sum region + cnt (contiguous: 3,250,000 floats)
    hipMemsetAsync(out, 0, (size_t)(N_NODES * 64 + N_NODES) * sizeof(float), stream);

    scatter_kernel<<<(N_EDGES * 64) / 256, 256, 0, stream>>>(efeats, dst, h, cnt);
    node_kernel<<<(N_NODES + 63) / 64, 64, 0, stream>>>(nfeats, Wa, ba, cnt, h);
    edge_kernel<<<N_EDGES / 128, 128, 0, stream>>>(efeats, src, dst, h, We, be, eh);
}

// Round 3
// 779.711 us; speedup vs baseline: 2.8365x; 2.8365x over previous
//
#include <hip/hip_runtime.h>
#include <hip/hip_bf16.h>

#define N_NODES 50000
#define N_EDGES 800000
#define NSCANB 49   // ceil(50000/1024)

typedef __attribute__((ext_vector_type(8))) __bf16 bf16x8;
typedef __attribute__((ext_vector_type(4))) float f32x4;

static __device__ __forceinline__ bf16x8 cvt8(float4 a, float4 b) {
    bf16x8 r;
    r[0] = (__bf16)a.x; r[1] = (__bf16)a.y; r[2] = (__bf16)a.z; r[3] = (__bf16)a.w;
    r[4] = (__bf16)b.x; r[5] = (__bf16)b.y; r[6] = (__bf16)b.z; r[7] = (__bf16)b.w;
    return r;
}

// ---------------------------------------------------------------------------
// CSR build: histogram -> 2-level exclusive scan -> bucket fill
// ---------------------------------------------------------------------------
__global__ void hist_kernel(const int* __restrict__ dst, int* __restrict__ deg) {
    int e = blockIdx.x * 256 + threadIdx.x;          // 3125 blocks exact
    atomicAdd(&deg[dst[e]], 1);
}

__global__ __launch_bounds__(1024) void scanA_kernel(const int* __restrict__ deg,
                                                     int* __restrict__ starts,
                                                     int* __restrict__ btot) {
    __shared__ int buf[1024];
    int t = threadIdx.x;
    int i = blockIdx.x * 1024 + t;
    int v = (i < N_NODES) ? deg[i] : 0;
    int val = v;
    buf[t] = v;
    __syncthreads();
    for (int off = 1; off < 1024; off <<= 1) {
        int add = (t >= off) ? buf[t - off] : 0;
        __syncthreads();
        val += add;
        buf[t] = val;
        __syncthreads();
    }
    if (i < N_NODES) starts[i] = val - v;            // block-local exclusive
    if (t == 1023) btot[blockIdx.x] = val;           // block total
}

__global__ void scanB_kernel(int* __restrict__ btot, int* __restrict__ starts) {
    if (threadIdx.x == 0 && blockIdx.x == 0) {
        int run = 0;
        for (int b = 0; b < NSCANB; ++b) { int v = btot[b]; btot[b] = run; run += v; }
        starts[N_NODES] = run;                       // == N_EDGES
    }
}

__global__ __launch_bounds__(1024) void scanC_kernel(int* __restrict__ starts,
                                                     int* __restrict__ cursor,
                                                     const int* __restrict__ btot) {
    int i = blockIdx.x * 1024 + threadIdx.x;
    if (i < N_NODES) {
        int s = starts[i] + btot[blockIdx.x];
        starts[i] = s;
        cursor[i] = s;
    }
}

__global__ void bucket_kernel(const int* __restrict__ dst, int* __restrict__ cursor,
                              int* __restrict__ csr) {
    int e = blockIdx.x * 256 + threadIdx.x;
    int p = atomicAdd(&cursor[dst[e]], 1);
    csr[p] = e;
}

// ---------------------------------------------------------------------------
// Gather-mean: one wave per node, lane = dim. Coalesced 256B row reads.
// ---------------------------------------------------------------------------
__global__ __launch_bounds__(256) void gather_kernel(const float* __restrict__ ef,
                                                     const int* __restrict__ starts,
                                                     const int* __restrict__ csr,
                                                     float* __restrict__ h_neigh) {
    int w = threadIdx.x >> 6, lane = threadIdx.x & 63;
    int n = blockIdx.x * 4 + w;
    if (n >= N_NODES) return;
    int s = starts[n], e_end = starts[n + 1];
    float s0 = 0.f, s1 = 0.f;
    int i = s;
    for (; i + 2 <= e_end; i += 2) {
        int e0 = csr[i], e1 = csr[i + 1];
        s0 += ef[(size_t)e0 * 64 + lane];
        s1 += ef[(size_t)e1 * 64 + lane];
    }
    if (i < e_end) s0 += ef[(size_t)csr[i] * 64 + lane];
    float cnt = (float)(e_end - s);
    h_neigh[(size_t)n * 64 + lane] = (s0 + s1) / fmaxf(cnt, 1.0f);
}

// ---------------------------------------------------------------------------
// Node MLP: h = relu(W_a [nfeat || h_neigh] + b). Thread per node, scalar W.
// ---------------------------------------------------------------------------
__global__ void __launch_bounds__(64) node_kernel(const float* __restrict__ nfeats,
                                                  const float* __restrict__ W,   // [64][128]
                                                  const float* __restrict__ bias,
                                                  const float* __restrict__ h_neigh,
                                                  float* __restrict__ h) {
    int n = blockIdx.x * 64 + threadIdx.x;
    if (n >= N_NODES) return;

    float acc[64];
#pragma unroll
    for (int j = 0; j < 64; ++j) acc[j] = bias[j];

    const float* __restrict__ xn = nfeats + (size_t)n * 64;
    const float* __restrict__ xs = h_neigh + (size_t)n * 64;

#pragma unroll 1
    for (int kc = 0; kc < 8; ++kc) {
        float xv[8];
#pragma unroll
        for (int i = 0; i < 8; ++i) xv[i] = xn[kc * 8 + i];
#pragma unroll
        for (int j = 0; j < 64; ++j)
#pragma unroll
            for (int i = 0; i < 8; ++i)
                acc[j] = fmaf(W[j * 128 + kc * 8 + i], xv[i], acc[j]);
    }
#pragma unroll 1
    for (int kc = 0; kc < 8; ++kc) {
        float xv[8];
#pragma unroll
        for (int i = 0; i < 8; ++i) xv[i] = xs[kc * 8 + i];
#pragma unroll
        for (int j = 0; j < 64; ++j)
#pragma unroll
            for (int i = 0; i < 8; ++i)
                acc[j] = fmaf(W[j * 128 + 64 + kc * 8 + i], xv[i], acc[j]);
    }

    float* out = h + (size_t)n * 64;
#pragma unroll
    for (int j = 0; j < 64; j += 4) {
        float4 v = make_float4(fmaxf(acc[j + 0], 0.0f), fmaxf(acc[j + 1], 0.0f),
                               fmaxf(acc[j + 2], 0.0f), fmaxf(acc[j + 3], 0.0f));
        *(float4*)(out + j) = v;
    }
}

// ---------------------------------------------------------------------------
// Edge MLP via MFMA 16x16x32 bf16:  eh[E,64] = relu( X[E,192] * We^T + be )
// A = We (row = out-dim, k), B = X^T (k, col = edge).
//   A frag: row = lane&15 (out), k = (lane>>4)*8 + j  -> from LDS W tile
//   B frag: col = lane&15 (edge), k = (lane>>4)*8 + j -> gathered h (f32->bf16)
//                                                        + LDS ef tile
//   D frag: col = lane&15 (edge), row = (lane>>4)*4 + reg (out) -> float4 store
// Block: 256 threads = 4 waves; 256 edges/block; wave owns 64 edges (4 groups).
// LDS: W [64][200] bf16 (pad->2-way banks) + ef [256][72] bf16 = 62.5 KB.
// ---------------------------------------------------------------------------
__global__ __launch_bounds__(256) void edge_mfma_kernel(
    const float* __restrict__ efeats, const int* __restrict__ src_,
    const int* __restrict__ dst_, const float* __restrict__ h,
    const float* __restrict__ We,   // [64][192] f32
    const float* __restrict__ be, float* __restrict__ eh) {
    __shared__ __bf16 Wl[64][200];
    __shared__ __bf16 efl[256][72];
    const int t = threadIdx.x;
    const int ebase = blockIdx.x * 256;

    // stage We -> LDS (bf16). 12288 elems = 1536 chunks of 8.
    for (int i = t; i < 1536; i += 256) {
        int r = i / 24, c = (i % 24) * 8;
        const float* wp = We + r * 192 + c;
        float4 w0 = *(const float4*)wp;
        float4 w1 = *(const float4*)(wp + 4);
        *(bf16x8*)&Wl[r][c] = cvt8(w0, w1);
    }
    // stage efeats rows [ebase, ebase+256) -> LDS bf16. 16384 f32 = 2048 chunks.
    for (int i = t; i < 2048; i += 256) {
        int r = i >> 3, c = (i & 7) * 8;
        const float* p = efeats + (size_t)(ebase + r) * 64 + c;
        float4 a = *(const float4*)p;
        float4 b = *(const float4*)(p + 4);
        *(bf16x8*)&efl[r][c] = cvt8(a, b);
    }
    __syncthreads();

    const int wid = t >> 6, lane = t & 63;
    const int r16 = lane & 15;        // A: out row | B: edge col | D: edge col
    const int g = lane >> 4;          // k-group / D row-group

    float4 bv[4];
#pragma unroll
    for (int m = 0; m < 4; ++m) bv[m] = *(const float4*)(be + m * 16 + g * 4);

#pragma unroll 1
    for (int grp = 0; grp < 4; ++grp) {
        const int erow = wid * 64 + grp * 16 + r16;   // edge row in block tile
        const int e = ebase + erow;
        const int s = src_[e], d = dst_[e];
        const float* ps = h + (size_t)s * 64;
        const float* pd = h + (size_t)d * 64;

        // B fragments: k-chunks 0..5 (h_src, h_src, h_dst, h_dst, ef, ef)
        bf16x8 bfr[6];
        {
            float4 a0 = *(const float4*)(ps + g * 8);
            float4 a1 = *(const float4*)(ps + g * 8 + 4);
            float4 a2 = *(const float4*)(ps + 32 + g * 8);
            float4 a3 = *(const float4*)(ps + 32 + g * 8 + 4);
            bfr[0] = cvt8(a0, a1);
            bfr[1] = cvt8(a2, a3);
            float4 b0 = *(const float4*)(pd + g * 8);
            float4 b1 = *(const float4*)(pd + g * 8 + 4);
            float4 b2 = *(const float4*)(pd + 32 + g * 8);
            float4 b3 = *(const float4*)(pd + 32 + g * 8 + 4);
            bfr[2] = cvt8(b0, b1);
            bfr[3] = cvt8(b2, b3);
            bfr[4] = *(const bf16x8*)&efl[erow][g * 8];
            bfr[5] = *(const bf16x8*)&efl[erow][32 + g * 8];
        }

        f32x4 acc[4] = {{0,0,0,0},{0,0,0,0},{0,0,0,0},{0,0,0,0}};
#pragma unroll
        for (int c = 0; c < 6; ++c) {
#pragma unroll
            for (int m = 0; m < 4; ++m) {
                bf16x8 a = *(const bf16x8*)&Wl[m * 16 + r16][c * 32 + g * 8];
                acc[m] = __builtin_amdgcn_mfma_f32_16x16x32_bf16(a, bfr[c], acc[m], 0, 0, 0);
            }
        }

        float* op = eh + (size_t)e * 64 + g * 4;
#pragma unroll
        for (int m = 0; m < 4; ++m) {
            float4 o = make_float4(fmaxf(acc[m][0] + bv[m].x, 0.0f),
                                   fmaxf(acc[m][1] + bv[m].y, 0.0f),
                                   fmaxf(acc[m][2] + bv[m].z, 0.0f),
                                   fmaxf(acc[m][3] + bv[m].w, 0.0f));
            *(float4*)(op + m * 16) = o;
        }
    }
}

// ---------------------------------------------------------------------------
extern "C" void kernel_launch(void* const* d_in, const int* in_sizes, int n_in,
                              void* d_out, int out_size, void* d_ws, size_t ws_size,
                              hipStream_t stream) {
    const float* nfeats = (const float*)d_in[0];
    const float* efeats = (const float*)d_in[1];
    const int*   src    = (const int*)d_in[2];
    const int*   dst    = (const int*)d_in[3];
    const float* Wa     = (const float*)d_in[4];
    const float* ba     = (const float*)d_in[5];
    const float* We     = (const float*)d_in[6];
    const float* be     = (const float*)d_in[7];

    float* out = (float*)d_out;
    float* h   = out;                               // [50000*64] final h
    float* eh  = out + (size_t)N_NODES * 64;        // [800000*64] final eh

    // Scratch inside the (not-yet-written) tail of the eh region.
    // eh region = 51.2M floats; scratch at eh+30M spans < 7.5M ints. All
    // consumed before edge_mfma_kernel overwrites the region.
    int*   scratch = (int*)(eh + 30000000);
    int*   deg     = scratch;                       // 50000
    int*   starts  = scratch + 262144;              // 50001
    int*   cursor  = scratch + 524288;              // 50000
    int*   btot    = scratch + 786432;              // 49
    int*   csr     = scratch + 1048576;             // 800000
    float* h_neigh = (float*)(scratch + 4194304);   // 50000*64 f32

    hipMemsetAsync(deg, 0, N_NODES * sizeof(int), stream);

    hist_kernel <<<N_EDGES / 256, 256, 0, stream>>>(dst, deg);
    scanA_kernel<<<NSCANB, 1024, 0, stream>>>(deg, starts, btot);
    scanB_kernel<<<1, 64, 0, stream>>>(btot, starts);
    scanC_kernel<<<NSCANB, 1024, 0, stream>>>(starts, cursor, btot);
    bucket_kernel<<<N_EDGES / 256, 256, 0, stream>>>(dst, cursor, csr);
    gather_kernel<<<(N_NODES + 3) / 4, 256, 0, stream>>>(efeats, starts, csr, h_neigh);
    node_kernel <<<(N_NODES + 63) / 64, 64, 0, stream>>>(nfeats, Wa, ba, h_neigh, h);
    edge_mfma_kernel<<<N_EDGES / 256, 256, 0, stream>>>(efeats, src, dst, h, We, be, eh);
}

// Round 5
// 721.943 us; speedup vs baseline: 3.0635x; 1.0800x over previous
//
#include <hip/hip_runtime.h>
#include <hip/hip_bf16.h>

#define N_NODES 50000
#define N_EDGES 800000
#define SCHUNK 49   // 1024*49 = 50176 >= 50000

typedef __attribute__((ext_vector_type(8))) __bf16 bf16x8;
typedef __attribute__((ext_vector_type(4))) float f32x4;

static __device__ __forceinline__ bf16x8 cvt8(float4 a, float4 b) {
    bf16x8 r;
    r[0] = (__bf16)a.x; r[1] = (__bf16)a.y; r[2] = (__bf16)a.z; r[3] = (__bf16)a.w;
    r[4] = (__bf16)b.x; r[5] = (__bf16)b.y; r[6] = (__bf16)b.z; r[7] = (__bf16)b.w;
    return r;
}

// ---------------------------------------------------------------------------
// CSR build: histogram -> single-block scan -> bucket fill
// ---------------------------------------------------------------------------
__global__ void hist_kernel(const int* __restrict__ dst, int* __restrict__ deg) {
    int e = blockIdx.x * 256 + threadIdx.x;          // 3125 blocks exact
    atomicAdd(&deg[dst[e]], 1);
}

// One block, 1024 threads: thread t owns deg[t*49 .. t*49+48]; serial sum,
// block-scan partials, serial exclusive write-out of starts+cursor.
__global__ __launch_bounds__(1024) void scan_kernel(const int* __restrict__ deg,
                                                    int* __restrict__ starts,
                                                    int* __restrict__ cursor) {
    __shared__ int buf[1024];
    int t = threadIdx.x;
    int lo = t * SCHUNK, hi = min(lo + SCHUNK, N_NODES);
    int sum = 0;
    for (int i = lo; i < hi; ++i) sum += deg[i];
    buf[t] = sum;
    __syncthreads();
    int val = sum;
    for (int off = 1; off < 1024; off <<= 1) {
        int add = (t >= off) ? buf[t - off] : 0;
        __syncthreads();
        val += add;
        buf[t] = val;
        __syncthreads();
    }
    int run = val - sum;                             // exclusive prefix of chunk
    for (int i = lo; i < hi; ++i) {
        starts[i] = run; cursor[i] = run; run += deg[i];
    }
    if (t == 1023) starts[N_NODES] = run;            // == N_EDGES
}

__global__ void bucket_kernel(const int* __restrict__ dst, int* __restrict__ cursor,
                              int* __restrict__ csr) {
    int e = blockIdx.x * 256 + threadIdx.x;
    int p = atomicAdd(&cursor[dst[e]], 1);
    csr[p] = e;
}

// ---------------------------------------------------------------------------
// Gather-mean: one wave per node, lane = dim. Coalesced 256B row reads.
// ---------------------------------------------------------------------------
__global__ __launch_bounds__(256) void gather_kernel(const float* __restrict__ ef,
                                                     const int* __restrict__ starts,
                                                     const int* __restrict__ csr,
                                                     float* __restrict__ h_neigh) {
    int w = threadIdx.x >> 6, lane = threadIdx.x & 63;
    int n = blockIdx.x * 4 + w;
    if (n >= N_NODES) return;
    int s = starts[n], e_end = starts[n + 1];
    float s0 = 0.f, s1 = 0.f;
    int i = s;
    for (; i + 2 <= e_end; i += 2) {
        int e0 = csr[i], e1 = csr[i + 1];
        s0 += ef[(size_t)e0 * 64 + lane];
        s1 += ef[(size_t)e1 * 64 + lane];
    }
    if (i < e_end) s0 += ef[(size_t)csr[i] * 64 + lane];
    float cnt = (float)(e_end - s);
    h_neigh[(size_t)n * 64 + lane] = (s0 + s1) / fmaxf(cnt, 1.0f);
}

// ---------------------------------------------------------------------------
// Node MLP via MFMA 16x16x32 bf16: h[N,64] = relu( [nf||hn][N,128] * Wa^T + ba )
// Same fragment scheme as edge kernel (verified): A=Wa rows=out, B=X^T cols=node.
// 256 threads = 4 waves, 256 nodes/block, 4 k-chunks. Wa in LDS; X direct global.
// ---------------------------------------------------------------------------
__global__ __launch_bounds__(256) void node_mfma_kernel(
    const float* __restrict__ nfeats, const float* __restrict__ hn,
    const float* __restrict__ Wa,   // [64][128] f32
    const float* __restrict__ ba, float* __restrict__ h) {
    __shared__ __bf16 Wl[64][136];
    const int t = threadIdx.x;
    const int nbase = blockIdx.x * 256;

    // stage Wa -> LDS bf16. 8192 elems = 1024 chunks of 8.
    for (int i = t; i < 1024; i += 256) {
        int r = i >> 4, c = (i & 15) * 8;
        const float* wp = Wa + r * 128 + c;
        float4 w0 = *(const float4*)wp;
        float4 w1 = *(const float4*)(wp + 4);
        *(bf16x8*)&Wl[r][c] = cvt8(w0, w1);
    }
    __syncthreads();

    const int wid = t >> 6, lane = t & 63;
    const int r16 = lane & 15;        // A: out row | B: node col | D: node col
    const int g = lane >> 4;          // k-group / D row-group

    float4 bv[4];
#pragma unroll
    for (int m = 0; m < 4; ++m) bv[m] = *(const float4*)(ba + m * 16 + g * 4);

#pragma unroll 1
    for (int grp = 0; grp < 4; ++grp) {
        const int n = nbase + wid * 64 + grp * 16 + r16;
        const int nc = (n < N_NODES) ? n : (N_NODES - 1);   // clamp loads
        const float* p0 = nfeats + (size_t)nc * 64;
        const float* p1 = hn + (size_t)nc * 64;

        bf16x8 bfr[4];
        {
            float4 a0 = *(const float4*)(p0 + g * 8);
            float4 a1 = *(const float4*)(p0 + g * 8 + 4);
            float4 a2 = *(const float4*)(p0 + 32 + g * 8);
            float4 a3 = *(const float4*)(p0 + 32 + g * 8 + 4);
            bfr[0] = cvt8(a0, a1);
            bfr[1] = cvt8(a2, a3);
            float4 b0 = *(const float4*)(p1 + g * 8);
            float4 b1 = *(const float4*)(p1 + g * 8 + 4);
            float4 b2 = *(const float4*)(p1 + 32 + g * 8);
            float4 b3 = *(const float4*)(p1 + 32 + g * 8 + 4);
            bfr[2] = cvt8(b0, b1);
            bfr[3] = cvt8(b2, b3);
        }

        f32x4 acc[4] = {{0,0,0,0},{0,0,0,0},{0,0,0,0},{0,0,0,0}};
#pragma unroll
        for (int c = 0; c < 4; ++c) {
#pragma unroll
            for (int m = 0; m < 4; ++m) {
                bf16x8 a = *(const bf16x8*)&Wl[m * 16 + r16][c * 32 + g * 8];
                acc[m] = __builtin_amdgcn_mfma_f32_16x16x32_bf16(a, bfr[c], acc[m], 0, 0, 0);
            }
        }

        if (n < N_NODES) {
            float* op = h + (size_t)n * 64 + g * 4;
#pragma unroll
            for (int m = 0; m < 4; ++m) {
                float4 o = make_float4(fmaxf(acc[m][0] + bv[m].x, 0.0f),
                                       fmaxf(acc[m][1] + bv[m].y, 0.0f),
                                       fmaxf(acc[m][2] + bv[m].z, 0.0f),
                                       fmaxf(acc[m][3] + bv[m].w, 0.0f));
                *(float4*)(op + m * 16) = o;
            }
        }
    }
}

// ---------------------------------------------------------------------------
// Edge MLP via MFMA 16x16x32 bf16:  eh[E,64] = relu( X[E,192] * We^T + be )
// Block: 256 threads = 4 waves; 256 edges/block; wave owns 64 edges (4 groups).
// LDS: W [64][200] bf16 + ef [256][72] bf16 = 62.5 KB.
// ---------------------------------------------------------------------------
__global__ __launch_bounds__(256) void edge_mfma_kernel(
    const float* __restrict__ efeats, const int* __restrict__ src_,
    const int* __restrict__ dst_, const float* __restrict__ h,
    const float* __restrict__ We,   // [64][192] f32
    const float* __restrict__ be, float* __restrict__ eh) {
    __shared__ __bf16 Wl[64][200];
    __shared__ __bf16 efl[256][72];
    const int t = threadIdx.x;
    const int ebase = blockIdx.x * 256;

    // stage We -> LDS (bf16). 12288 elems = 1536 chunks of 8.
    for (int i = t; i < 1536; i += 256) {
        int r = i / 24, c = (i % 24) * 8;
        const float* wp = We + r * 192 + c;
        float4 w0 = *(const float4*)wp;
        float4 w1 = *(const float4*)(wp + 4);
        *(bf16x8*)&Wl[r][c] = cvt8(w0, w1);
    }
    // stage efeats rows [ebase, ebase+256) -> LDS bf16. 16384 f32 = 2048 chunks.
    for (int i = t; i < 2048; i += 256) {
        int r = i >> 3, c = (i & 7) * 8;
        const float* p = efeats + (size_t)(ebase + r) * 64 + c;
        float4 a = *(const float4*)p;
        float4 b = *(const float4*)(p + 4);
        *(bf16x8*)&efl[r][c] = cvt8(a, b);
    }
    __syncthreads();

    const int wid = t >> 6, lane = t & 63;
    const int r16 = lane & 15;        // A: out row | B: edge col | D: edge col
    const int g = lane >> 4;          // k-group / D row-group

    float4 bv[4];
#pragma unroll
    for (int m = 0; m < 4; ++m) bv[m] = *(const float4*)(be + m * 16 + g * 4);

#pragma unroll 1
    for (int grp = 0; grp < 4; ++grp) {
        const int erow = wid * 64 + grp * 16 + r16;   // edge row in block tile
        const int e = ebase + erow;
        const int s = src_[e], d = dst_[e];
        const float* ps = h + (size_t)s * 64;
        const float* pd = h + (size_t)d * 64;

        // B fragments: k-chunks 0..5 (h_src, h_src, h_dst, h_dst, ef, ef)
        bf16x8 bfr[6];
        {
            float4 a0 = *(const float4*)(ps + g * 8);
            float4 a1 = *(const float4*)(ps + g * 8 + 4);
            float4 a2 = *(const float4*)(ps + 32 + g * 8);
            float4 a3 = *(const float4*)(ps + 32 + g * 8 + 4);
            bfr[0] = cvt8(a0, a1);
            bfr[1] = cvt8(a2, a3);
            float4 b0 = *(const float4*)(pd + g * 8);
            float4 b1 = *(const float4*)(pd + g * 8 + 4);
            float4 b2 = *(const float4*)(pd + 32 + g * 8);
            float4 b3 = *(const float4*)(pd + 32 + g * 8 + 4);
            bfr[2] = cvt8(b0, b1);
            bfr[3] = cvt8(b2, b3);
            bfr[4] = *(const bf16x8*)&efl[erow][g * 8];
            bfr[5] = *(const bf16x8*)&efl[erow][32 + g * 8];
        }

        f32x4 acc[4] = {{0,0,0,0},{0,0,0,0},{0,0,0,0},{0,0,0,0}};
#pragma unroll
        for (int c = 0; c < 6; ++c) {
#pragma unroll
            for (int m = 0; m < 4; ++m) {
                bf16x8 a = *(const bf16x8*)&Wl[m * 16 + r16][c * 32 + g * 8];
                acc[m] = __builtin_amdgcn_mfma_f32_16x16x32_bf16(a, bfr[c], acc[m], 0, 0, 0);
            }
        }

        float* op = eh + (size_t)e * 64 + g * 4;
#pragma unroll
        for (int m = 0; m < 4; ++m) {
            float4 o = make_float4(fmaxf(acc[m][0] + bv[m].x, 0.0f),
                                   fmaxf(acc[m][1] + bv[m].y, 0.0f),
                                   fmaxf(acc[m][2] + bv[m].z, 0.0f),
                                   fmaxf(acc[m][3] + bv[m].w, 0.0f));
            *(float4*)(op + m * 16) = o;
        }
    }
}

// ---------------------------------------------------------------------------
extern "C" void kernel_launch(void* const* d_in, const int* in_sizes, int n_in,
                              void* d_out, int out_size, void* d_ws, size_t ws_size,
                              hipStream_t stream) {
    const float* nfeats = (const float*)d_in[0];
    const float* efeats = (const float*)d_in[1];
    const int*   src    = (const int*)d_in[2];
    const int*   dst    = (const int*)d_in[3];
    const float* Wa     = (const float*)d_in[4];
    const float* ba     = (const float*)d_in[5];
    const float* We     = (const float*)d_in[6];
    const float* be     = (const float*)d_in[7];

    float* out = (float*)d_out;
    float* h   = out;                               // [50000*64] final h
    float* eh  = out + (size_t)N_NODES * 64;        // [800000*64] final eh

    // Scratch inside the (not-yet-written) tail of the eh region; all consumed
    // before edge_mfma_kernel overwrites it.
    int*   scratch = (int*)(eh + 30000000);
    int*   deg     = scratch;                       // 50000
    int*   starts  = scratch + 262144;              // 50001
    int*   cursor  = scratch + 524288;              // 50000
    int*   csr     = scratch + 1048576;             // 800000
    float* h_neigh = (float*)(scratch + 4194304);   // 50000*64 f32

    hipMemsetAsync(deg, 0, N_NODES * sizeof(int), stream);

    hist_kernel  <<<N_EDGES / 256, 256, 0, stream>>>(dst, deg);
    scan_kernel  <<<1, 1024, 0, stream>>>(deg, starts, cursor);
    bucket_kernel<<<N_EDGES / 256, 256, 0, stream>>>(dst, cursor, csr);
    gather_kernel<<<(N_NODES + 3) / 4, 256, 0, stream>>>(efeats, starts, csr, h_neigh);
    node_mfma_kernel<<<(N_NODES + 255) / 256, 256, 0, stream>>>(nfeats, h_neigh, Wa, ba, h);
    edge_mfma_kernel<<<N_EDGES / 256, 256, 0, stream>>>(efeats, src, dst, h, We, be, eh);
}